// Round 7
// baseline (158.392 us; speedup 1.0000x reference)
//
#include <hip/hip_runtime.h>
#include <hip/hip_fp16.h>
#include <math.h>

#define B_ 128
#define N_ 512
#define C_ 128
#define W_ 128
#define LDSW 136  // padded row stride (halves); b128 access = uniform bank spread

typedef _Float16 f16;
typedef _Float16 f16x8 __attribute__((ext_vector_type(8)));
typedef _Float16 f16x4 __attribute__((ext_vector_type(4)));
typedef float f32x4 __attribute__((ext_vector_type(4)));

#define MFMA16(a, b, c) __builtin_amdgcn_mfma_f32_16x16x32_f16(a, b, c, 0, 0, 0)

#define LOG2E 1.44269504f
#define MASKF (-1e-6f * LOG2E)  // faithful -1e-6 fill, log2 domain

// ---------------------------------------------------------------------------
// K0: transpose Wq/Wk/Wv (fp32 [C][W]) -> fp16 WT[w][c]. grid(3 mats, 8 slabs)
// ---------------------------------------------------------------------------
__global__ __launch_bounds__(256) void prep_w(const float* __restrict__ Wq,
                                              const float* __restrict__ Wk,
                                              const float* __restrict__ Wv,
                                              f16* __restrict__ wT) {
  __shared__ float xs[16 * 129];
  const float* src = blockIdx.x == 0 ? Wq : (blockIdx.x == 1 ? Wk : Wv);
  f16* dst = wT + (size_t)blockIdx.x * C_ * W_;
  const int c0 = blockIdx.y * 16;
  const int t = threadIdx.x;
  for (int ii = 0; ii < 2; ++ii) {
    int idx = t + 256 * ii;           // 512 float4 = 16 rows x 32
    int row = idx >> 5, w4 = idx & 31;
    float4 v = *reinterpret_cast<const float4*>(src + (c0 + row) * W_ + w4 * 4);
    xs[row * 129 + w4 * 4 + 0] = v.x;
    xs[row * 129 + w4 * 4 + 1] = v.y;
    xs[row * 129 + w4 * 4 + 2] = v.z;
    xs[row * 129 + w4 * 4 + 3] = v.w;
  }
  __syncthreads();
  int o = t * 8;
  int w = o >> 4, cc = o & 15;        // cc in {0,8}
  f16x8 h;
  for (int jj = 0; jj < 8; ++jj) h[jj] = (f16)xs[(cc + jj) * 129 + w];
  *reinterpret_cast<f16x8*>(dst + w * C_ + c0 + cc) = h;
}

// ---------------------------------------------------------------------------
// K1: fused QKV projection v5 (unchanged from R5 — confirmed win).
// ---------------------------------------------------------------------------
__global__ __launch_bounds__(256, 2) void proj(const float* __restrict__ x,
                                               const float* __restrict__ bq,
                                               const float* __restrict__ bk,
                                               const float* __restrict__ bv,
                                               const f16* __restrict__ wT,
                                               f16* __restrict__ q,
                                               f16* __restrict__ k,
                                               f16* __restrict__ vT) {
  __shared__ f16 wls[2][128 * LDSW];
  const int b = blockIdx.y, n0 = blockIdx.x * 128;
  const int t = threadIdx.x, wave = t >> 6, lane = t & 63;
  const int quad = lane >> 4, l15 = lane & 15;

  float4 xr[2][4][2];
  for (int tile = 0; tile < 2; ++tile)
    for (int ks = 0; ks < 4; ++ks) {
      const float* p = x + ((size_t)(b * N_ + n0 + wave * 32 + tile * 16 +
                                     l15)) * C_ + ks * 32 + quad * 8;
      xr[tile][ks][0] = *reinterpret_cast<const float4*>(p);
      xr[tile][ks][1] = *reinterpret_cast<const float4*>(p + 4);
    }

  for (int i = 0; i < 8; ++i) {
    int idx = t + 256 * i;  // 2048 x 16B
    f16x8 tmp = *reinterpret_cast<const f16x8*>(wT + (size_t)idx * 8);
    *reinterpret_cast<f16x8*>(&wls[0][(idx >> 4) * LDSW + (idx & 15) * 8]) =
        tmp;
  }

  f16x8 af[2][4];
  for (int tile = 0; tile < 2; ++tile)
    for (int ks = 0; ks < 4; ++ks) {
      f16x8 h;
      h[0] = (f16)xr[tile][ks][0].x; h[1] = (f16)xr[tile][ks][0].y;
      h[2] = (f16)xr[tile][ks][0].z; h[3] = (f16)xr[tile][ks][0].w;
      h[4] = (f16)xr[tile][ks][1].x; h[5] = (f16)xr[tile][ks][1].y;
      h[6] = (f16)xr[tile][ks][1].z; h[7] = (f16)xr[tile][ks][1].w;
      af[tile][ks] = h;
    }
  __syncthreads();  // lds[0] ready

  for (int ph = 0; ph < 3; ++ph) {
    const f16* wl = wls[ph & 1];

    f16x8 wst[8];
    if (ph < 2)
      for (int i = 0; i < 8; ++i)
        wst[i] = *reinterpret_cast<const f16x8*>(
            wT + (size_t)(ph + 1) * 16384 + (size_t)(t + 256 * i) * 8);

    f32x4 acc[8][2];
    for (int ct = 0; ct < 8; ++ct) {
      acc[ct][0] = {0.f, 0.f, 0.f, 0.f};
      acc[ct][1] = {0.f, 0.f, 0.f, 0.f};
    }

    if (ph < 2) {
      for (int ct = 0; ct < 8; ++ct) {
        f16x8 wf[4];
        for (int ks = 0; ks < 4; ++ks)
          wf[ks] = *reinterpret_cast<const f16x8*>(
              &wl[(ct * 16 + l15) * LDSW + ks * 32 + quad * 8]);
        for (int ks = 0; ks < 4; ++ks) {
          acc[ct][0] = MFMA16(wf[ks], af[0][ks], acc[ct][0]);
          acc[ct][1] = MFMA16(wf[ks], af[1][ks], acc[ct][1]);
        }
      }
      const float* bias = ph == 0 ? bq : bk;
      const float scale = ph == 0 ? LOG2E : 1.0f;
      f16* dst = ph == 0 ? q : k;
      for (int ct = 0; ct < 8; ++ct) {
        const float4 bb =
            *reinterpret_cast<const float4*>(bias + ct * 16 + quad * 4);
        for (int tile = 0; tile < 2; ++tile) {
          int n = n0 + wave * 32 + tile * 16 + l15;
          f16x4 h;
          h.x = (f16)((acc[ct][tile][0] + bb.x) * scale);
          h.y = (f16)((acc[ct][tile][1] + bb.y) * scale);
          h.z = (f16)((acc[ct][tile][2] + bb.z) * scale);
          h.w = (f16)((acc[ct][tile][3] + bb.w) * scale);
          *reinterpret_cast<f16x4*>(dst + ((size_t)(b * N_ + n)) * W_ +
                                    ct * 16 + quad * 4) = h;
        }
      }
    } else {
      for (int ct = 0; ct < 8; ++ct) {
        f16x8 wf[4];
        for (int ks = 0; ks < 4; ++ks)
          wf[ks] = *reinterpret_cast<const f16x8*>(
              &wl[(ct * 16 + l15) * LDSW + ks * 32 + quad * 8]);
        for (int ks = 0; ks < 4; ++ks) {
          acc[ct][0] = MFMA16(af[0][ks], wf[ks], acc[ct][0]);
          acc[ct][1] = MFMA16(af[1][ks], wf[ks], acc[ct][1]);
        }
      }
      for (int ct = 0; ct < 8; ++ct) {
        int wcol = ct * 16 + l15;
        float bb = bv[wcol];
        for (int tile = 0; tile < 2; ++tile) {
          int n = n0 + wave * 32 + tile * 16 + quad * 4;
          f16x4 h;
          h.x = (f16)(acc[ct][tile][0] + bb);
          h.y = (f16)(acc[ct][tile][1] + bb);
          h.z = (f16)(acc[ct][tile][2] + bb);
          h.w = (f16)(acc[ct][tile][3] + bb);
          *reinterpret_cast<f16x4*>(&vT[((size_t)(b * W_ + wcol)) * N_ + n]) =
              h;
        }
      }
    }

    if (ph < 2) {
      for (int i = 0; i < 8; ++i) {
        int idx = t + 256 * i;
        *reinterpret_cast<f16x8*>(
            &wls[(ph + 1) & 1][(idx >> 4) * LDSW + (idx & 15) * 8]) = wst[i];
      }
      __syncthreads();
    }
  }
}

// ---------------------------------------------------------------------------
// K2: flash v6 — wave-private P, one adjacent barrier pair per chunk.
//   Wave owns 32 m-cols end-to-end: QK (K from shared LDS), softmax local,
//   P^T via wave-private LDS rows (lgkmcnt only), PV over ALL 128 w with
//   V^T direct from global (issued early, two 64-VGPR halves). Barriers only
//   bracket the kls(j+1) write; QK/softmax/PV run barrier-free. Last chunk
//   has no barriers. Faithful mask: n > valid_len[b] -> -1e-6 fill.
// ---------------------------------------------------------------------------
__global__ __launch_bounds__(256, 2) void flash(const f16* __restrict__ q,
                                                const f16* __restrict__ k,
                                                const f16* __restrict__ vT,
                                                const int* __restrict__ vlen,
                                                float* __restrict__ out) {
  __shared__ f16 kls[128 * LDSW];
  __shared__ f16 pls[128 * LDSW];
  const int b = blockIdx.x, m0 = blockIdx.y * 128;  // same-b WGs -> same XCD
  const int t = threadIdx.x, wave = t >> 6, lane = t & 63;
  const int quad = lane >> 4, l15 = lane & 15;
  const int vl = vlen[b];
  const int mcol = m0 + wave * 32;
  const int srow = t >> 4, sc16 = t & 15;  // staging coords (256 threads)

  // Q B-frags for this wave's 32 m-cols, held all kernel
  f16x8 qf[2][4];
  for (int ct = 0; ct < 2; ++ct)
    for (int kt = 0; kt < 4; ++kt)
      qf[ct][kt] = *reinterpret_cast<const f16x8*>(
          q + ((size_t)(b * N_ + mcol + ct * 16 + l15)) * W_ + kt * 32 +
          quad * 8);

  f32x4 oacc[8][2];  // [wt = all 128 w][ct = own m]
  for (int wt = 0; wt < 8; ++wt)
    for (int ct = 0; ct < 2; ++ct) oacc[wt][ct] = {0.f, 0.f, 0.f, 0.f};
  float mrun[2] = {-3.4e38f, -3.4e38f}, lrun[2] = {0.f, 0.f};

  // prologue: stage K(0)
  for (int i = 0; i < 8; ++i) {
    int row = srow + 16 * i;
    f16x8 tmp = *reinterpret_cast<const f16x8*>(
        k + ((size_t)(b * N_ + row)) * W_ + sc16 * 8);
    *reinterpret_cast<f16x8*>(&kls[row * LDSW + sc16 * 8]) = tmp;
  }
  __syncthreads();

  f16* prow = &pls[(size_t)wave * 32 * LDSW];  // wave-private 32 m rows

  for (int j = 0; j < 4; ++j) {
    const int n0 = j * 128;

    // K(j+1) prefetch, in flight across QK+softmax
    f16x8 kst[8];
    if (j < 3)
      for (int i = 0; i < 8; ++i)
        kst[i] = *reinterpret_cast<const f16x8*>(
            k + ((size_t)(b * N_ + n0 + 128 + srow + 16 * i)) * W_ + sc16 * 8);

    // QK: S^T slab (128 n x own 32 m) from shared kls
    f32x4 sacc[8][2];
    for (int i = 0; i < 8; ++i) {
      sacc[i][0] = {0.f, 0.f, 0.f, 0.f};
      sacc[i][1] = {0.f, 0.f, 0.f, 0.f};
      f16x8 kf[4];
      for (int kt = 0; kt < 4; ++kt)
        kf[kt] = *reinterpret_cast<const f16x8*>(
            &kls[(i * 16 + l15) * LDSW + kt * 32 + quad * 8]);
      for (int kt = 0; kt < 4; ++kt) {
        sacc[i][0] = MFMA16(kf[kt], qf[0][kt], sacc[i][0]);
        sacc[i][1] = MFMA16(kf[kt], qf[1][kt], sacc[i][1]);
      }
    }

    // mask (key index n = S^T row)
    for (int i = 0; i < 8; ++i)
      for (int r = 0; r < 4; ++r) {
        int n = n0 + 16 * i + quad * 4 + r;
        if (n > vl) { sacc[i][0][r] = MASKF; sacc[i][1][r] = MASKF; }
      }

    // wave-local online softmax (stats replicated across quads)
    float alpha[2];
    for (int ct = 0; ct < 2; ++ct) {
      float mx = -3.4e38f;
      for (int i = 0; i < 8; ++i)
        for (int r = 0; r < 4; ++r) mx = fmaxf(mx, sacc[i][ct][r]);
      mx = fmaxf(mx, __shfl_xor(mx, 16));
      mx = fmaxf(mx, __shfl_xor(mx, 32));
      float mnew = fmaxf(mrun[ct], mx);
      alpha[ct] = exp2f(mrun[ct] - mnew);
      mrun[ct] = mnew;
      float s = 0.f;
      for (int i = 0; i < 8; ++i)
        for (int r = 0; r < 4; ++r) {
          float p = exp2f(sacc[i][ct][r] - mnew);
          sacc[i][ct][r] = p;
          s += p;
        }
      s += __shfl_xor(s, 16);
      s += __shfl_xor(s, 32);
      lrun[ct] = lrun[ct] * alpha[ct] + s;
    }

    // P^T -> wave-private LDS rows (no barrier; lgkmcnt orders RAW)
    for (int i = 0; i < 8; ++i)
      for (int ct = 0; ct < 2; ++ct) {
        f16x4 h;
        h.x = (f16)sacc[i][ct][0];
        h.y = (f16)sacc[i][ct][1];
        h.z = (f16)sacc[i][ct][2];
        h.w = (f16)sacc[i][ct][3];
        *reinterpret_cast<f16x4*>(
            &prow[(ct * 16 + l15) * LDSW + 16 * i + quad * 4]) = h;
      }

    // V^T first half (wt 0..3), issued before the barrier pair
    f16x8 vf[4][4];
    for (int wt = 0; wt < 4; ++wt)
      for (int kt = 0; kt < 4; ++kt)
        vf[wt][kt] = *reinterpret_cast<const f16x8*>(
            vT + ((size_t)(b * W_ + 16 * wt + l15)) * N_ + n0 + kt * 32 +
            quad * 8);

    // adjacent barrier pair around the kls(j+1) write — only sync point
    if (j < 3) {
      __syncthreads();  // all waves' QK(j) reads of kls done
      for (int i = 0; i < 8; ++i)
        *reinterpret_cast<f16x8*>(&kls[(srow + 16 * i) * LDSW + sc16 * 8]) =
            kst[i];
      __syncthreads();  // kls(j+1) visible
    }

    // own P^T back as B-frags (b128, same-wave)
    f16x8 pf[2][4];
    for (int ct = 0; ct < 2; ++ct)
      for (int kt = 0; kt < 4; ++kt)
        pf[ct][kt] = *reinterpret_cast<const f16x8*>(
            &prow[(ct * 16 + l15) * LDSW + kt * 32 + quad * 8]);

    // rescale O, PV first half
    for (int wt = 0; wt < 8; ++wt) {
      oacc[wt][0] *= alpha[0];
      oacc[wt][1] *= alpha[1];
    }
    for (int wt = 0; wt < 4; ++wt)
      for (int kt = 0; kt < 4; ++kt) {
        oacc[wt][0] = MFMA16(vf[wt][kt], pf[0][kt], oacc[wt][0]);
        oacc[wt][1] = MFMA16(vf[wt][kt], pf[1][kt], oacc[wt][1]);
      }

    // V^T second half (wt 4..7), then PV second half
    for (int wt = 0; wt < 4; ++wt)
      for (int kt = 0; kt < 4; ++kt)
        vf[wt][kt] = *reinterpret_cast<const f16x8*>(
            vT + ((size_t)(b * W_ + 64 + 16 * wt + l15)) * N_ + n0 + kt * 32 +
            quad * 8);
    for (int wt = 0; wt < 4; ++wt)
      for (int kt = 0; kt < 4; ++kt) {
        oacc[4 + wt][0] = MFMA16(vf[wt][kt], pf[0][kt], oacc[4 + wt][0]);
        oacc[4 + wt][1] = MFMA16(vf[wt][kt], pf[1][kt], oacc[4 + wt][1]);
      }
  }

  // epilogue: O[m][w] = oacc / lrun — all wave-local, no sync
  for (int ct = 0; ct < 2; ++ct) {
    float inv = 1.f / lrun[ct];
    int m = mcol + ct * 16 + l15;
    for (int wt = 0; wt < 8; ++wt) {
      int w = 16 * wt + quad * 4;
      float4 o;
      o.x = oacc[wt][ct][0] * inv;
      o.y = oacc[wt][ct][1] * inv;
      o.z = oacc[wt][ct][2] * inv;
      o.w = oacc[wt][ct][3] * inv;
      *reinterpret_cast<float4*>(&out[((size_t)(b * N_ + m)) * W_ + w]) = o;
    }
  }
}

// ---------------------------------------------------------------------------
extern "C" void kernel_launch(void* const* d_in, const int* in_sizes, int n_in,
                              void* d_out, int out_size, void* d_ws,
                              size_t ws_size, hipStream_t stream) {
  const float* x  = (const float*)d_in[0];
  const float* Wq = (const float*)d_in[1];
  const float* bq = (const float*)d_in[2];
  const float* Wk = (const float*)d_in[3];
  const float* bk = (const float*)d_in[4];
  const float* Wv = (const float*)d_in[5];
  const float* bv = (const float*)d_in[6];
  const int* vlen = (const int*)d_in[7];
  float* out = (float*)d_out;

  char* ws = (char*)d_ws;
  f16* wT = (f16*)ws;
  f16* q  = (f16*)(ws + (1u << 20));
  f16* k  = (f16*)(ws + (1u << 20) + (16u << 20));
  f16* vT = (f16*)(ws + (1u << 20) + (32u << 20));

  prep_w<<<dim3(3, 8), 256, 0, stream>>>(Wq, Wk, Wv, wT);
  proj<<<dim3(4, 128), 256, 0, stream>>>(x, bq, bk, bv, wT, q, k, vT);
  flash<<<dim3(128, 4), 256, 0, stream>>>(q, k, vT, vlen, out);
}

// Round 8
// 140.954 us; speedup vs baseline: 1.1237x; 1.1237x over previous
//
#include <hip/hip_runtime.h>
#include <hip/hip_fp16.h>
#include <math.h>

#define B_ 128
#define N_ 512
#define C_ 128
#define W_ 128
#define LDSW 136  // padded row stride (halves); b128 access = uniform bank spread

typedef _Float16 f16;
typedef _Float16 f16x8 __attribute__((ext_vector_type(8)));
typedef _Float16 f16x4 __attribute__((ext_vector_type(4)));
typedef float f32x4 __attribute__((ext_vector_type(4)));

#define MFMA16(a, b, c) __builtin_amdgcn_mfma_f32_16x16x32_f16(a, b, c, 0, 0, 0)

#define LOG2E 1.44269504f
#define MASKF (-1e-6f * LOG2E)  // faithful -1e-6 fill, log2 domain

// ---------------------------------------------------------------------------
// K0: transpose Wq/Wk/Wv (fp32 [C][W]) -> fp16 WT[w][c]. grid(3 mats, 8 slabs)
// ---------------------------------------------------------------------------
__global__ __launch_bounds__(256) void prep_w(const float* __restrict__ Wq,
                                              const float* __restrict__ Wk,
                                              const float* __restrict__ Wv,
                                              f16* __restrict__ wT) {
  __shared__ float xs[16 * 129];
  const float* src = blockIdx.x == 0 ? Wq : (blockIdx.x == 1 ? Wk : Wv);
  f16* dst = wT + (size_t)blockIdx.x * C_ * W_;
  const int c0 = blockIdx.y * 16;
  const int t = threadIdx.x;
  for (int ii = 0; ii < 2; ++ii) {
    int idx = t + 256 * ii;           // 512 float4 = 16 rows x 32
    int row = idx >> 5, w4 = idx & 31;
    float4 v = *reinterpret_cast<const float4*>(src + (c0 + row) * W_ + w4 * 4);
    xs[row * 129 + w4 * 4 + 0] = v.x;
    xs[row * 129 + w4 * 4 + 1] = v.y;
    xs[row * 129 + w4 * 4 + 2] = v.z;
    xs[row * 129 + w4 * 4 + 3] = v.w;
  }
  __syncthreads();
  int o = t * 8;
  int w = o >> 4, cc = o & 15;        // cc in {0,8}
  f16x8 h;
  for (int jj = 0; jj < 8; ++jj) h[jj] = (f16)xs[(cc + jj) * 129 + w];
  *reinterpret_cast<f16x8*>(dst + w * C_ + c0 + cc) = h;
}

// ---------------------------------------------------------------------------
// K1: fused QKV projection v5 (unchanged — part of the 141.8 µs config).
// ---------------------------------------------------------------------------
__global__ __launch_bounds__(256, 2) void proj(const float* __restrict__ x,
                                               const float* __restrict__ bq,
                                               const float* __restrict__ bk,
                                               const float* __restrict__ bv,
                                               const f16* __restrict__ wT,
                                               f16* __restrict__ q,
                                               f16* __restrict__ k,
                                               f16* __restrict__ vT) {
  __shared__ f16 wls[2][128 * LDSW];
  const int b = blockIdx.y, n0 = blockIdx.x * 128;
  const int t = threadIdx.x, wave = t >> 6, lane = t & 63;
  const int quad = lane >> 4, l15 = lane & 15;

  float4 xr[2][4][2];
  for (int tile = 0; tile < 2; ++tile)
    for (int ks = 0; ks < 4; ++ks) {
      const float* p = x + ((size_t)(b * N_ + n0 + wave * 32 + tile * 16 +
                                     l15)) * C_ + ks * 32 + quad * 8;
      xr[tile][ks][0] = *reinterpret_cast<const float4*>(p);
      xr[tile][ks][1] = *reinterpret_cast<const float4*>(p + 4);
    }

  for (int i = 0; i < 8; ++i) {
    int idx = t + 256 * i;  // 2048 x 16B
    f16x8 tmp = *reinterpret_cast<const f16x8*>(wT + (size_t)idx * 8);
    *reinterpret_cast<f16x8*>(&wls[0][(idx >> 4) * LDSW + (idx & 15) * 8]) =
        tmp;
  }

  f16x8 af[2][4];
  for (int tile = 0; tile < 2; ++tile)
    for (int ks = 0; ks < 4; ++ks) {
      f16x8 h;
      h[0] = (f16)xr[tile][ks][0].x; h[1] = (f16)xr[tile][ks][0].y;
      h[2] = (f16)xr[tile][ks][0].z; h[3] = (f16)xr[tile][ks][0].w;
      h[4] = (f16)xr[tile][ks][1].x; h[5] = (f16)xr[tile][ks][1].y;
      h[6] = (f16)xr[tile][ks][1].z; h[7] = (f16)xr[tile][ks][1].w;
      af[tile][ks] = h;
    }
  __syncthreads();  // lds[0] ready

  for (int ph = 0; ph < 3; ++ph) {
    const f16* wl = wls[ph & 1];

    f16x8 wst[8];
    if (ph < 2)
      for (int i = 0; i < 8; ++i)
        wst[i] = *reinterpret_cast<const f16x8*>(
            wT + (size_t)(ph + 1) * 16384 + (size_t)(t + 256 * i) * 8);

    f32x4 acc[8][2];
    for (int ct = 0; ct < 8; ++ct) {
      acc[ct][0] = {0.f, 0.f, 0.f, 0.f};
      acc[ct][1] = {0.f, 0.f, 0.f, 0.f};
    }

    if (ph < 2) {
      for (int ct = 0; ct < 8; ++ct) {
        f16x8 wf[4];
        for (int ks = 0; ks < 4; ++ks)
          wf[ks] = *reinterpret_cast<const f16x8*>(
              &wl[(ct * 16 + l15) * LDSW + ks * 32 + quad * 8]);
        for (int ks = 0; ks < 4; ++ks) {
          acc[ct][0] = MFMA16(wf[ks], af[0][ks], acc[ct][0]);
          acc[ct][1] = MFMA16(wf[ks], af[1][ks], acc[ct][1]);
        }
      }
      const float* bias = ph == 0 ? bq : bk;
      const float scale = ph == 0 ? LOG2E : 1.0f;
      f16* dst = ph == 0 ? q : k;
      for (int ct = 0; ct < 8; ++ct) {
        const float4 bb =
            *reinterpret_cast<const float4*>(bias + ct * 16 + quad * 4);
        for (int tile = 0; tile < 2; ++tile) {
          int n = n0 + wave * 32 + tile * 16 + l15;
          f16x4 h;
          h.x = (f16)((acc[ct][tile][0] + bb.x) * scale);
          h.y = (f16)((acc[ct][tile][1] + bb.y) * scale);
          h.z = (f16)((acc[ct][tile][2] + bb.z) * scale);
          h.w = (f16)((acc[ct][tile][3] + bb.w) * scale);
          *reinterpret_cast<f16x4*>(dst + ((size_t)(b * N_ + n)) * W_ +
                                    ct * 16 + quad * 4) = h;
        }
      }
    } else {
      for (int ct = 0; ct < 8; ++ct) {
        f16x8 wf[4];
        for (int ks = 0; ks < 4; ++ks)
          wf[ks] = *reinterpret_cast<const f16x8*>(
              &wl[(ct * 16 + l15) * LDSW + ks * 32 + quad * 8]);
        for (int ks = 0; ks < 4; ++ks) {
          acc[ct][0] = MFMA16(af[0][ks], wf[ks], acc[ct][0]);
          acc[ct][1] = MFMA16(af[1][ks], wf[ks], acc[ct][1]);
        }
      }
      for (int ct = 0; ct < 8; ++ct) {
        int wcol = ct * 16 + l15;
        float bb = bv[wcol];
        for (int tile = 0; tile < 2; ++tile) {
          int n = n0 + wave * 32 + tile * 16 + quad * 4;
          f16x4 h;
          h.x = (f16)(acc[ct][tile][0] + bb);
          h.y = (f16)(acc[ct][tile][1] + bb);
          h.z = (f16)(acc[ct][tile][2] + bb);
          h.w = (f16)(acc[ct][tile][3] + bb);
          *reinterpret_cast<f16x4*>(&vT[((size_t)(b * W_ + wcol)) * N_ + n]) =
              h;
        }
      }
    }

    if (ph < 2) {
      for (int i = 0; i < 8; ++i) {
        int idx = t + 256 * i;
        *reinterpret_cast<f16x8*>(
            &wls[(ph + 1) & 1][(idx >> 4) * LDSW + (idx & 15) * 8]) = wst[i];
      }
      __syncthreads();
    }
  }
}

// ---------------------------------------------------------------------------
// K2: flash v7 = v5 (cooperative K staging + K-prefetch, w-split PV with
//     non-redundant per-wave V, shared-LDS P^T, 2 barriers/chunk) with V
//     loads HOISTED: wt=0 half issued at chunk top (QK+softmax covers its
//     latency), wt=1 half before bar2 (drain+kls-write+rescale covers it).
//     Faithful mask: key n > valid_len[b] -> fill -1e-6 (participates).
// ---------------------------------------------------------------------------
__global__ __launch_bounds__(256, 2) void flash(const f16* __restrict__ q,
                                                const f16* __restrict__ k,
                                                const f16* __restrict__ vT,
                                                const int* __restrict__ vlen,
                                                float* __restrict__ out) {
  __shared__ f16 kls[128 * LDSW];
  __shared__ f16 pls[128 * LDSW];
  __shared__ float bcast[128];
  const int b = blockIdx.x, m0 = blockIdx.y * 128;  // same-b WGs -> same XCD
  const int t = threadIdx.x, wave = t >> 6, lane = t & 63;
  const int quad = lane >> 4, l15 = lane & 15;
  const int vl = vlen[b];
  const int mcol = m0 + wave * 32;
  const int srow = t >> 4, sc16 = t & 15;  // staging coords (256 threads)

  // Q B-frags for this wave's 32 m-cols, held all kernel
  f16x8 qf[2][4];
  for (int ct = 0; ct < 2; ++ct)
    for (int kt = 0; kt < 4; ++kt)
      qf[ct][kt] = *reinterpret_cast<const f16x8*>(
          q + ((size_t)(b * N_ + mcol + ct * 16 + l15)) * W_ + kt * 32 +
          quad * 8);

  f32x4 oacc[2][8];  // [wt (this wave's w)][cm (all 128 m)]
  for (int wt = 0; wt < 2; ++wt)
    for (int cm = 0; cm < 8; ++cm) oacc[wt][cm] = {0.f, 0.f, 0.f, 0.f};
  float mrun[2] = {-3.4e38f, -3.4e38f}, lrun[2] = {0.f, 0.f};

  // prologue: stage K(0)
  for (int i = 0; i < 8; ++i) {
    int row = srow + 16 * i;
    f16x8 tmp = *reinterpret_cast<const f16x8*>(
        k + ((size_t)(b * N_ + row)) * W_ + sc16 * 8);
    *reinterpret_cast<f16x8*>(&kls[row * LDSW + sc16 * 8]) = tmp;
  }
  __syncthreads();  // bar1(0)

  for (int j = 0; j < 4; ++j) {
    const int n0 = j * 128;

    // V^T wt=0 half for this wave's w-slab — issued at top, full-chunk cover
    f16x8 vfa[4];
    for (int kt = 0; kt < 4; ++kt)
      vfa[kt] = *reinterpret_cast<const f16x8*>(
          vT + ((size_t)(b * W_ + wave * 32 + l15)) * N_ + n0 + kt * 32 +
          quad * 8);

    // K(j+1) prefetch (in flight across QK+softmax)
    f16x8 kst[8];
    if (j < 3)
      for (int i = 0; i < 8; ++i)
        kst[i] = *reinterpret_cast<const f16x8*>(
            k + ((size_t)(b * N_ + n0 + 128 + srow + 16 * i)) * W_ + sc16 * 8);

    // QK: S^T slab (128 n x wave's 32 m)
    f32x4 sacc[8][2];
    for (int i = 0; i < 8; ++i) {
      sacc[i][0] = {0.f, 0.f, 0.f, 0.f};
      sacc[i][1] = {0.f, 0.f, 0.f, 0.f};
      f16x8 kf[4];
      for (int kt = 0; kt < 4; ++kt)
        kf[kt] = *reinterpret_cast<const f16x8*>(
            &kls[(i * 16 + l15) * LDSW + kt * 32 + quad * 8]);
      for (int kt = 0; kt < 4; ++kt) {
        sacc[i][0] = MFMA16(kf[kt], qf[0][kt], sacc[i][0]);
        sacc[i][1] = MFMA16(kf[kt], qf[1][kt], sacc[i][1]);
      }
    }

    // mask (key index n = S^T row)
    for (int i = 0; i < 8; ++i)
      for (int r = 0; r < 4; ++r) {
        int n = n0 + 16 * i + quad * 4 + r;
        if (n > vl) { sacc[i][0][r] = MASKF; sacc[i][1][r] = MASKF; }
      }

    // wave-local online softmax (stats replicated across quads)
    float alpha[2];
    for (int ct = 0; ct < 2; ++ct) {
      float mx = -3.4e38f;
      for (int i = 0; i < 8; ++i)
        for (int r = 0; r < 4; ++r) mx = fmaxf(mx, sacc[i][ct][r]);
      mx = fmaxf(mx, __shfl_xor(mx, 16));
      mx = fmaxf(mx, __shfl_xor(mx, 32));
      float mnew = fmaxf(mrun[ct], mx);
      alpha[ct] = exp2f(mrun[ct] - mnew);
      mrun[ct] = mnew;
      float s = 0.f;
      for (int i = 0; i < 8; ++i)
        for (int r = 0; r < 4; ++r) {
          float p = exp2f(sacc[i][ct][r] - mnew);
          sacc[i][ct][r] = p;
          s += p;
        }
      s += __shfl_xor(s, 16);
      s += __shfl_xor(s, 32);
      lrun[ct] = lrun[ct] * alpha[ct] + s;
    }

    // write P^T slab (wave-own 32 m rows x 128 n) + alpha broadcast
    for (int i = 0; i < 8; ++i)
      for (int ct = 0; ct < 2; ++ct) {
        f16x4 h;
        h.x = (f16)sacc[i][ct][0];
        h.y = (f16)sacc[i][ct][1];
        h.z = (f16)sacc[i][ct][2];
        h.w = (f16)sacc[i][ct][3];
        *reinterpret_cast<f16x4*>(
            &pls[(wave * 32 + ct * 16 + l15) * LDSW + 16 * i + quad * 4]) = h;
      }
    if (quad == 0) {
      bcast[wave * 32 + l15] = alpha[0];
      bcast[wave * 32 + 16 + l15] = alpha[1];
    }

    // V^T wt=1 half (drain + kls-write + rescale cover its latency)
    f16x8 vfb[4];
    for (int kt = 0; kt < 4; ++kt)
      vfb[kt] = *reinterpret_cast<const f16x8*>(
          vT + ((size_t)(b * W_ + wave * 32 + 16 + l15)) * N_ + n0 + kt * 32 +
          quad * 8);
    __syncthreads();  // bar2: pls+bcast visible; all kls(j) reads done

    // write prefetched K(j+1) into kls (readers wait at loop-end barrier)
    if (j < 3)
      for (int i = 0; i < 8; ++i)
        *reinterpret_cast<f16x8*>(&kls[(srow + 16 * i) * LDSW + sc16 * 8]) =
            kst[i];

    // rescale O by alpha of each m-col, then PV over all 128 m
    float al[8];
    for (int cm = 0; cm < 8; ++cm) al[cm] = bcast[cm * 16 + l15];
    for (int wt = 0; wt < 2; ++wt)
      for (int cm = 0; cm < 8; ++cm) oacc[wt][cm] *= al[cm];
    for (int cm = 0; cm < 8; ++cm) {
      f16x8 pf[4];
      for (int kt = 0; kt < 4; ++kt)
        pf[kt] = *reinterpret_cast<const f16x8*>(
            &pls[(cm * 16 + l15) * LDSW + kt * 32 + quad * 8]);
      for (int kt = 0; kt < 4; ++kt) {
        oacc[0][cm] = MFMA16(vfa[kt], pf[kt], oacc[0][cm]);
        oacc[1][cm] = MFMA16(vfb[kt], pf[kt], oacc[1][cm]);
      }
    }
    __syncthreads();  // bar1(j+1): kls(j+1) visible; pls reads done
  }

  // epilogue: broadcast 1/l, scale, store O[m][w] (float4, w contiguous)
  if (quad == 0) {
    bcast[wave * 32 + l15] = 1.f / lrun[0];
    bcast[wave * 32 + 16 + l15] = 1.f / lrun[1];
  }
  __syncthreads();
  for (int cm = 0; cm < 8; ++cm) {
    float inv = bcast[cm * 16 + l15];
    int m = m0 + cm * 16 + l15;
    for (int wt = 0; wt < 2; ++wt) {
      int w = wave * 32 + wt * 16 + quad * 4;
      float4 o;
      o.x = oacc[wt][cm][0] * inv;
      o.y = oacc[wt][cm][1] * inv;
      o.z = oacc[wt][cm][2] * inv;
      o.w = oacc[wt][cm][3] * inv;
      *reinterpret_cast<float4*>(&out[((size_t)(b * N_ + m)) * W_ + w]) = o;
    }
  }
}

// ---------------------------------------------------------------------------
extern "C" void kernel_launch(void* const* d_in, const int* in_sizes, int n_in,
                              void* d_out, int out_size, void* d_ws,
                              size_t ws_size, hipStream_t stream) {
  const float* x  = (const float*)d_in[0];
  const float* Wq = (const float*)d_in[1];
  const float* bq = (const float*)d_in[2];
  const float* Wk = (const float*)d_in[3];
  const float* bk = (const float*)d_in[4];
  const float* Wv = (const float*)d_in[5];
  const float* bv = (const float*)d_in[6];
  const int* vlen = (const int*)d_in[7];
  float* out = (float*)d_out;

  char* ws = (char*)d_ws;
  f16* wT = (f16*)ws;
  f16* q  = (f16*)(ws + (1u << 20));
  f16* k  = (f16*)(ws + (1u << 20) + (16u << 20));
  f16* vT = (f16*)(ws + (1u << 20) + (32u << 20));

  prep_w<<<dim3(3, 8), 256, 0, stream>>>(Wq, Wk, Wv, wT);
  proj<<<dim3(4, 128), 256, 0, stream>>>(x, bq, bk, bv, wT, q, k, vT);
  flash<<<dim3(128, 4), 256, 0, stream>>>(q, k, vT, vlen, out);
}